// Round 1
// baseline (508.689 us; speedup 1.0000x reference)
//
#include <hip/hip_runtime.h>

#define T_TOK   32768
#define HDIM    2048
#define NEXP    8
#define SEQ     8192
#define NBATCH  4
#define ALPHA   0.1f

#define BLOCK   256
#define CHUNK   32                 // tokens per block (divides SEQ)
#define NBLK    (T_TOK / CHUNK)    // 1024

// ---------------------------------------------------------------- init ws
__global__ __launch_bounds__(64) void init_ws_kernel(float* ws) {
    ws[threadIdx.x] = 0.0f;        // 64 floats: [0..31] pi_sum, [32..63] ce_cnt
}

// ---------------------------------------------------------------- main gate
__global__ __launch_bounds__(BLOCK) void gate_kernel(
    const float* __restrict__ x,      // [T_TOK, HDIM]
    const float* __restrict__ w,      // [NEXP, HDIM]
    float* __restrict__ out_idx,      // [T_TOK, 2] (float-encoded ints)
    float* __restrict__ out_wt,       // [T_TOK, 2]
    float* __restrict__ ws)           // [64] accumulators
{
    __shared__ float4 wlds[NEXP * (HDIM / 4)];   // 64 KB exactly

    const int tid = threadIdx.x;

    // Stage gate weights: 4096 float4s, 16 per thread, coalesced.
    const float4* w4 = (const float4*)w;
    #pragma unroll
    for (int i = 0; i < 16; ++i)
        wlds[tid + i * BLOCK] = w4[tid + i * BLOCK];
    __syncthreads();

    const int wid  = tid >> 6;
    const int lane = tid & 63;
    const int tok_base = blockIdx.x * CHUNK;
    const int b = tok_base / SEQ;               // uniform per block

    float pi_part[NEXP];
    float ce_part[NEXP];
    #pragma unroll
    for (int e = 0; e < NEXP; ++e) { pi_part[e] = 0.f; ce_part[e] = 0.f; }

    const float4* x4 = (const float4*)x;

    for (int g = 0; g < 2; ++g) {               // 2 groups of M=4 tokens per wave
        const int tg = tok_base + wid * 8 + g * 4;

        float acc[4][NEXP];
        #pragma unroll
        for (int m = 0; m < 4; ++m)
            #pragma unroll
            for (int e = 0; e < NEXP; ++e) acc[m][e] = 0.f;

        // software-pipelined x loads (double buffer in regs)
        float4 xv[4];
        #pragma unroll
        for (int m = 0; m < 4; ++m)
            xv[m] = x4[(size_t)(tg + m) * (HDIM / 4) + lane];

        #pragma unroll
        for (int it = 0; it < 8; ++it) {
            float4 xc[4];
            #pragma unroll
            for (int m = 0; m < 4; ++m) xc[m] = xv[m];
            if (it < 7) {
                #pragma unroll
                for (int m = 0; m < 4; ++m)
                    xv[m] = x4[(size_t)(tg + m) * (HDIM / 4) + (it + 1) * 64 + lane];
            }
            #pragma unroll
            for (int e = 0; e < NEXP; ++e) {
                const float4 wv = wlds[e * (HDIM / 4) + it * 64 + lane];
                #pragma unroll
                for (int m = 0; m < 4; ++m) {
                    acc[m][e] = fmaf(xc[m].x, wv.x, acc[m][e]);
                    acc[m][e] = fmaf(xc[m].y, wv.y, acc[m][e]);
                    acc[m][e] = fmaf(xc[m].z, wv.z, acc[m][e]);
                    acc[m][e] = fmaf(xc[m].w, wv.w, acc[m][e]);
                }
            }
        }

        // reduce each (m,e) partial across 64 lanes (butterfly -> all lanes)
        #pragma unroll
        for (int m = 0; m < 4; ++m)
            #pragma unroll
            for (int e = 0; e < NEXP; ++e) {
                float v = acc[m][e];
                v += __shfl_xor(v, 1);
                v += __shfl_xor(v, 2);
                v += __shfl_xor(v, 4);
                v += __shfl_xor(v, 8);
                v += __shfl_xor(v, 16);
                v += __shfl_xor(v, 32);
                acc[m][e] = v;
            }

        // per-token epilogue (computed redundantly; lane m owns token tg+m)
        #pragma unroll
        for (int m = 0; m < 4; ++m) {
            float l[NEXP];
            #pragma unroll
            for (int e = 0; e < NEXP; ++e) l[e] = acc[m][e];

            float mx = l[0];
            #pragma unroll
            for (int e = 1; e < NEXP; ++e) mx = fmaxf(mx, l[e]);

            float p[NEXP];
            float psum = 0.f;
            #pragma unroll
            for (int e = 0; e < NEXP; ++e) { p[e] = __expf(l[e] - mx); psum += p[e]; }
            const float inv = 1.0f / psum;
            float s[NEXP];
            #pragma unroll
            for (int e = 0; e < NEXP; ++e) s[e] = p[e] * inv;

            // top-1 (strict > keeps lowest index on ties, matching lax.top_k)
            float s1 = s[0]; int i1 = 0;
            #pragma unroll
            for (int e = 1; e < NEXP; ++e)
                if (s[e] > s1) { s1 = s[e]; i1 = e; }
            // top-2
            float s2 = -1.f; int i2 = 0;
            #pragma unroll
            for (int e = 0; e < NEXP; ++e)
                if (e != i1 && s[e] > s2) { s2 = s[e]; i2 = e; }

            const float wsum = s1 + s2 + 1e-20f;
            const float w1 = s1 / wsum;
            const float w2 = s2 / wsum;

            if (lane == m) {
                const int t = tg + m;
                ((float2*)out_idx)[t] = make_float2((float)i1, (float)i2);
                ((float2*)out_wt)[t]  = make_float2(w1, w2);
                #pragma unroll
                for (int e = 0; e < NEXP; ++e) {
                    pi_part[e] += s[e];
                    ce_part[e] += (i1 == e ? 1.f : 0.f) + (i2 == e ? 1.f : 0.f);
                }
            }
        }
    }

    // only lanes 0..3 hold contributions -> 2-stage reduce puts total on lane 0
    #pragma unroll
    for (int e = 0; e < NEXP; ++e) {
        float v = pi_part[e];
        v += __shfl_xor(v, 1);
        v += __shfl_xor(v, 2);
        pi_part[e] = v;
        float c = ce_part[e];
        c += __shfl_xor(c, 1);
        c += __shfl_xor(c, 2);
        ce_part[e] = c;
    }
    if (lane == 0) {
        #pragma unroll
        for (int e = 0; e < NEXP; ++e) {
            atomicAdd(&ws[b * NEXP + e], pi_part[e]);
            atomicAdd(&ws[32 + b * NEXP + e], ce_part[e]);
        }
    }
}

// ---------------------------------------------------------------- finalize
__global__ __launch_bounds__(64) void finalize_kernel(const float* __restrict__ ws,
                                                      float* __restrict__ out_aux) {
    if (threadIdx.x == 0) {
        float aux = 0.f;
        #pragma unroll
        for (int b = 0; b < NBATCH; ++b) {
            float dot = 0.f;
            #pragma unroll
            for (int e = 0; e < NEXP; ++e) {
                const float ce = ws[32 + b * NEXP + e] * ((float)NEXP / (float)(SEQ * 2));
                const float pi = ws[b * NEXP + e] / (float)SEQ;
                dot = fmaf(ce, pi, dot);
            }
            aux += dot;
        }
        out_aux[0] = aux * (1.0f / NBATCH) * ALPHA;
    }
}

// ---------------------------------------------------------------- launch
extern "C" void kernel_launch(void* const* d_in, const int* in_sizes, int n_in,
                              void* d_out, int out_size, void* d_ws, size_t ws_size,
                              hipStream_t stream) {
    const float* x = (const float*)d_in[0];   // hidden_states [4,8192,2048]
    const float* w = (const float*)d_in[1];   // weight [8,2048]

    float* out     = (float*)d_out;
    float* out_idx = out;                  // [32768,2]
    float* out_wt  = out + 2 * T_TOK;      // [32768,2]
    float* out_aux = out + 4 * T_TOK;      // [1]
    float* ws      = (float*)d_ws;

    init_ws_kernel<<<1, 64, 0, stream>>>(ws);
    gate_kernel<<<NBLK, BLOCK, 0, stream>>>(x, w, out_idx, out_wt, ws);
    finalize_kernel<<<1, 64, 0, stream>>>(ws, out_aux);
}

// Round 2
// 90.109 us; speedup vs baseline: 5.6453x; 5.6453x over previous
//
#include <hip/hip_runtime.h>

#define T_TOK   32768
#define HDIM    2048
#define NEXP    8
#define SEQ     8192
#define NBATCH  4
#define ALPHA   0.1f

#define BLOCK   256
#define TOK_PER_BLOCK 16               // 4 waves x 4 tokens
#define NBLK    (T_TOK / TOK_PER_BLOCK)  // 2048
#define H4      (HDIM / 4)             // 512 float4 per row
#define NJ      (H4 / 16)              // 32 float4 steps per lane (16-lane split)

// ---------------------------------------------------------------- init ws
__global__ __launch_bounds__(64) void init_ws_kernel(float* ws) {
    ws[threadIdx.x] = 0.0f;            // [0..31] pi_sum, [32..63] ce_cnt
}

// ---------------------------------------------------------------- main gate
__global__ __launch_bounds__(BLOCK, 4) void gate_kernel(
    const float* __restrict__ x,       // [T_TOK, HDIM]
    const float* __restrict__ w,       // [NEXP, HDIM]
    float* __restrict__ out_idx,       // [T_TOK, 2] float-encoded
    float* __restrict__ out_wt,        // [T_TOK, 2]
    float* __restrict__ ws)            // [64]
{
    __shared__ float sacc[16];         // block-level aux partials (8 pi + 8 ce)

    const int tid  = threadIdx.x;
    const int wid  = tid >> 6;
    const int lane = tid & 63;
    const int grp  = lane >> 4;        // which of the wave's 4 tokens
    const int col  = lane & 15;        // H-slice lane within token group

    if (tid < 16) sacc[tid] = 0.0f;

    const int tok = blockIdx.x * TOK_PER_BLOCK + wid * 4 + grp;
    const int b   = (blockIdx.x * TOK_PER_BLOCK) / SEQ;   // uniform per block

    const float4* xp = (const float4*)x + (size_t)tok * H4 + col;
    const float4* wp = (const float4*)w + col;

    float acc[NEXP];
    #pragma unroll
    for (int e = 0; e < NEXP; ++e) acc[e] = 0.0f;

    // register double-buffer: slot0 / slot1, static indexing only
    float4 xb0, xb1;
    float4 wb0[NEXP], wb1[NEXP];

    xb0 = xp[0];
    #pragma unroll
    for (int e = 0; e < NEXP; ++e) wb0[e] = wp[e * H4];

    #pragma unroll 1
    for (int j = 0; j < NJ; j += 2) {
        // prefetch j+1 into slot1 (always valid: NJ even)
        xb1 = xp[(j + 1) * 16];
        #pragma unroll
        for (int e = 0; e < NEXP; ++e) wb1[e] = wp[e * H4 + (j + 1) * 16];

        // compute slot0 (j)
        #pragma unroll
        for (int e = 0; e < NEXP; ++e) {
            acc[e] = fmaf(xb0.x, wb0[e].x, acc[e]);
            acc[e] = fmaf(xb0.y, wb0[e].y, acc[e]);
            acc[e] = fmaf(xb0.z, wb0[e].z, acc[e]);
            acc[e] = fmaf(xb0.w, wb0[e].w, acc[e]);
        }

        // prefetch j+2 into slot0
        if (j + 2 < NJ) {
            xb0 = xp[(j + 2) * 16];
            #pragma unroll
            for (int e = 0; e < NEXP; ++e) wb0[e] = wp[e * H4 + (j + 2) * 16];
        }

        // compute slot1 (j+1)
        #pragma unroll
        for (int e = 0; e < NEXP; ++e) {
            acc[e] = fmaf(xb1.x, wb1[e].x, acc[e]);
            acc[e] = fmaf(xb1.y, wb1[e].y, acc[e]);
            acc[e] = fmaf(xb1.z, wb1[e].z, acc[e]);
            acc[e] = fmaf(xb1.w, wb1[e].w, acc[e]);
        }
    }

    // reduce each expert-partial across the 16-lane group (4 groups in parallel)
    #pragma unroll
    for (int e = 0; e < NEXP; ++e) {
        float v = acc[e];
        v += __shfl_xor(v, 1);
        v += __shfl_xor(v, 2);
        v += __shfl_xor(v, 4);
        v += __shfl_xor(v, 8);
        acc[e] = v;                    // all 16 lanes of the group hold full logits
    }

    // lane-local softmax + top-2 for this lane's token
    float mx = acc[0];
    #pragma unroll
    for (int e = 1; e < NEXP; ++e) mx = fmaxf(mx, acc[e]);

    float p[NEXP];
    float psum = 0.0f;
    #pragma unroll
    for (int e = 0; e < NEXP; ++e) { p[e] = __expf(acc[e] - mx); psum += p[e]; }
    const float inv = 1.0f / psum;
    float s[NEXP];
    #pragma unroll
    for (int e = 0; e < NEXP; ++e) s[e] = p[e] * inv;

    float s1 = s[0]; int i1 = 0;       // strict > keeps lowest index (lax.top_k)
    #pragma unroll
    for (int e = 1; e < NEXP; ++e) if (s[e] > s1) { s1 = s[e]; i1 = e; }
    float s2 = -1.0f; int i2 = 0;
    #pragma unroll
    for (int e = 0; e < NEXP; ++e) if (e != i1 && s[e] > s2) { s2 = s[e]; i2 = e; }

    const float wsum = s1 + s2 + 1e-20f;
    const float w1 = s1 / wsum;
    const float w2 = s2 / wsum;

    if (col == 0) {
        ((float2*)out_idx)[tok] = make_float2((float)i1, (float)i2);
        ((float2*)out_wt)[tok]  = make_float2(w1, w2);
    }

    // aux partials: only col==0 lanes contribute (one lane per token)
    const float sel = (col == 0) ? 1.0f : 0.0f;
    __syncthreads();                    // sacc zero-init visible
    #pragma unroll
    for (int e = 0; e < NEXP; ++e) {
        float pi = s[e] * sel;
        float ce = (((i1 == e) ? 1.0f : 0.0f) + ((i2 == e) ? 1.0f : 0.0f)) * sel;
        // sum the 4 token-groups of this wave (lanes 0,16,32,48 hold data)
        pi += __shfl_xor(pi, 16); pi += __shfl_xor(pi, 32);
        ce += __shfl_xor(ce, 16); ce += __shfl_xor(ce, 32);
        if (lane == 0) {
            atomicAdd(&sacc[e], pi);
            atomicAdd(&sacc[8 + e], ce);
        }
    }
    __syncthreads();
    if (tid < 8)                        // 8 pi + 8 ce global atomics per block
        atomicAdd(&ws[b * NEXP + tid], sacc[tid]);
    else if (tid < 16)
        atomicAdd(&ws[32 + b * NEXP + (tid - 8)], sacc[tid]);
}

// ---------------------------------------------------------------- finalize
__global__ __launch_bounds__(64) void finalize_kernel(const float* __restrict__ ws,
                                                      float* __restrict__ out_aux) {
    if (threadIdx.x == 0) {
        float aux = 0.0f;
        #pragma unroll
        for (int b = 0; b < NBATCH; ++b) {
            float dot = 0.0f;
            #pragma unroll
            for (int e = 0; e < NEXP; ++e) {
                const float ce = ws[32 + b * NEXP + e] * ((float)NEXP / (float)(SEQ * 2));
                const float pi = ws[b * NEXP + e] / (float)SEQ;
                dot = fmaf(ce, pi, dot);
            }
            aux += dot;
        }
        out_aux[0] = aux * (1.0f / NBATCH) * ALPHA;
    }
}

// ---------------------------------------------------------------- launch
extern "C" void kernel_launch(void* const* d_in, const int* in_sizes, int n_in,
                              void* d_out, int out_size, void* d_ws, size_t ws_size,
                              hipStream_t stream) {
    const float* x = (const float*)d_in[0];   // hidden_states [4,8192,2048]
    const float* w = (const float*)d_in[1];   // weight [8,2048]

    float* out     = (float*)d_out;
    float* out_idx = out;                  // [32768,2]
    float* out_wt  = out + 2 * T_TOK;      // [32768,2]
    float* out_aux = out + 4 * T_TOK;      // [1]
    float* ws      = (float*)d_ws;

    init_ws_kernel<<<1, 64, 0, stream>>>(ws);
    gate_kernel<<<NBLK, BLOCK, 0, stream>>>(x, w, out_idx, out_wt, ws);
    finalize_kernel<<<1, 64, 0, stream>>>(ws, out_aux);
}

// Round 3
// 79.666 us; speedup vs baseline: 6.3853x; 1.1311x over previous
//
#include <hip/hip_runtime.h>

#define T_TOK   32768
#define HDIM    2048
#define NEXP    8
#define SEQ     8192
#define NBATCH  4
#define ALPHA   0.1f

#define BLOCK   256
#define TPB     32                 // tokens per block: 4 waves x 8
#define NBLK    (T_TOK / TPB)      // 1024
#define H4      (HDIM / 4)         // 512 float4 per row
#define NJ      (H4 / 16)          // 32 j-phases (16-lane H split)

// ---------------------------------------------------------------- init ws
__global__ __launch_bounds__(64) void init_ws_kernel(float* ws) {
    ws[threadIdx.x] = 0.0f;        // [0..31] pi_sum, [32..63] ce_cnt
}

// ---------------------------------------------------------------- main gate
// Wave = 4 groups of 16 lanes; each group owns 2 consecutive tokens.
// Pipeline per j-phase: computeA | load wA(j+1) | computeB | load wB(j+1) | load x(j+2).
__global__ __launch_bounds__(BLOCK, 4) void gate_kernel(
    const float* __restrict__ x,       // [T_TOK, HDIM]
    const float* __restrict__ w,       // [NEXP, HDIM]
    float* __restrict__ out_idx,       // [T_TOK, 2] float-encoded
    float* __restrict__ out_wt,        // [T_TOK, 2]
    float* __restrict__ ws)            // [64]
{
    __shared__ float sacc[16];

    const int tid  = threadIdx.x;
    const int wid  = tid >> 6;
    const int lane = tid & 63;
    const int grp  = lane >> 4;
    const int col  = lane & 15;

    if (tid < 16) sacc[tid] = 0.0f;

    const int tok0 = blockIdx.x * TPB + wid * 8 + grp * 2;   // group's 1st token
    const int b    = (blockIdx.x * TPB) / SEQ;               // uniform per block

    const float4* xp0 = (const float4*)x + (size_t)tok0 * H4 + col;
    const float4* xp1 = xp0 + H4;                            // 2nd token
    const float4* wp  = (const float4*)w + col;

    float acc[2][NEXP];
    #pragma unroll
    for (int t = 0; t < 2; ++t)
        #pragma unroll
        for (int e = 0; e < NEXP; ++e) acc[t][e] = 0.0f;

    float4 xb0[2], xb1[2];             // x slots for even/odd j (2 tokens each)
    float4 wA[4], wB[4];               // expert halves for current j

    // prologue: x(0), x(1), w(0,A), w(0,B)
    xb0[0] = xp0[0];        xb0[1] = xp1[0];
    xb1[0] = xp0[16];       xb1[1] = xp1[16];
    #pragma unroll
    for (int e = 0; e < 4; ++e) wA[e] = wp[e * H4];
    #pragma unroll
    for (int e = 0; e < 4; ++e) wB[e] = wp[(e + 4) * H4];

#define FMA4(ACC, XV, WV)                      \
    ACC = fmaf((XV).x, (WV).x, ACC);           \
    ACC = fmaf((XV).y, (WV).y, ACC);           \
    ACC = fmaf((XV).z, (WV).z, ACC);           \
    ACC = fmaf((XV).w, (WV).w, ACC);

#define COMPUTE_HALF(XB, WH, EBASE)            \
    _Pragma("unroll")                          \
    for (int e = 0; e < 4; ++e) {              \
        const float4 wv = WH[e];               \
        FMA4(acc[0][(EBASE) + e], XB[0], wv);  \
        FMA4(acc[1][(EBASE) + e], XB[1], wv);  \
    }

    #pragma unroll 1
    for (int jj = 0; jj < NJ - 2; jj += 2) {
        // ---- phase j = jj (even slot)
        COMPUTE_HALF(xb0, wA, 0)
        #pragma unroll
        for (int e = 0; e < 4; ++e) wA[e] = wp[e * H4 + (jj + 1) * 16];
        COMPUTE_HALF(xb0, wB, 4)
        #pragma unroll
        for (int e = 0; e < 4; ++e) wB[e] = wp[(e + 4) * H4 + (jj + 1) * 16];
        xb0[0] = xp0[(jj + 2) * 16];
        xb0[1] = xp1[(jj + 2) * 16];

        // ---- phase j = jj+1 (odd slot)
        COMPUTE_HALF(xb1, wA, 0)
        #pragma unroll
        for (int e = 0; e < 4; ++e) wA[e] = wp[e * H4 + (jj + 2) * 16];
        COMPUTE_HALF(xb1, wB, 4)
        #pragma unroll
        for (int e = 0; e < 4; ++e) wB[e] = wp[(e + 4) * H4 + (jj + 2) * 16];
        xb1[0] = xp0[(jj + 3) * 16];
        xb1[1] = xp1[(jj + 3) * 16];
    }

    // ---- peeled tail: jj = NJ-2 (phases 30, 31; no x prefetch, one w prefetch)
    {
        COMPUTE_HALF(xb0, wA, 0)
        #pragma unroll
        for (int e = 0; e < 4; ++e) wA[e] = wp[e * H4 + (NJ - 1) * 16];
        COMPUTE_HALF(xb0, wB, 4)
        #pragma unroll
        for (int e = 0; e < 4; ++e) wB[e] = wp[(e + 4) * H4 + (NJ - 1) * 16];
        COMPUTE_HALF(xb1, wA, 0)
        COMPUTE_HALF(xb1, wB, 4)
    }

    // reduce partials across the 16-lane group (4 groups in parallel)
    #pragma unroll
    for (int t = 0; t < 2; ++t)
        #pragma unroll
        for (int e = 0; e < NEXP; ++e) {
            float v = acc[t][e];
            v += __shfl_xor(v, 1);
            v += __shfl_xor(v, 2);
            v += __shfl_xor(v, 4);
            v += __shfl_xor(v, 8);
            acc[t][e] = v;             // all 16 lanes hold both tokens' logits
        }

    // lane-local epilogue: lane col handles token (col & 1); only col<2 commits
    const int t = col & 1;
    float l[NEXP];
    #pragma unroll
    for (int e = 0; e < NEXP; ++e) l[e] = acc[t][e];

    float mx = l[0];
    #pragma unroll
    for (int e = 1; e < NEXP; ++e) mx = fmaxf(mx, l[e]);

    float p[NEXP];
    float psum = 0.0f;
    #pragma unroll
    for (int e = 0; e < NEXP; ++e) { p[e] = __expf(l[e] - mx); psum += p[e]; }
    const float inv = 1.0f / psum;
    float s[NEXP];
    #pragma unroll
    for (int e = 0; e < NEXP; ++e) s[e] = p[e] * inv;

    float s1 = s[0]; int i1 = 0;       // strict > keeps lowest index (lax.top_k)
    #pragma unroll
    for (int e = 1; e < NEXP; ++e) if (s[e] > s1) { s1 = s[e]; i1 = e; }
    float s2 = -1.0f; int i2 = 0;
    #pragma unroll
    for (int e = 0; e < NEXP; ++e) if (e != i1 && s[e] > s2) { s2 = s[e]; i2 = e; }

    const float wsum = s1 + s2 + 1e-20f;
    const float w1 = s1 / wsum;
    const float w2 = s2 / wsum;

    if (col < 2) {
        const int tok = tok0 + t;
        ((float2*)out_idx)[tok] = make_float2((float)i1, (float)i2);
        ((float2*)out_wt)[tok]  = make_float2(w1, w2);
    }

    // aux partials: lanes col 0,1 of each group carry their token's stats
    const float sel = (col < 2) ? 1.0f : 0.0f;
    __syncthreads();                    // sacc zero-init visible
    #pragma unroll
    for (int e = 0; e < NEXP; ++e) {
        float pi = s[e] * sel;
        float ce = (((i1 == e) ? 1.0f : 0.0f) + ((i2 == e) ? 1.0f : 0.0f)) * sel;
        pi += __shfl_xor(pi, 1);  ce += __shfl_xor(ce, 1);   // token pair
        pi += __shfl_xor(pi, 16); ce += __shfl_xor(ce, 16);  // groups
        pi += __shfl_xor(pi, 32); ce += __shfl_xor(ce, 32);
        if (lane == 0) {
            atomicAdd(&sacc[e], pi);
            atomicAdd(&sacc[8 + e], ce);
        }
    }
    __syncthreads();
    if (tid < 8)
        atomicAdd(&ws[b * NEXP + tid], sacc[tid]);
    else if (tid < 16)
        atomicAdd(&ws[32 + b * NEXP + (tid - 8)], sacc[tid]);
}

// ---------------------------------------------------------------- finalize
__global__ __launch_bounds__(64) void finalize_kernel(const float* __restrict__ ws,
                                                      float* __restrict__ out_aux) {
    if (threadIdx.x == 0) {
        float aux = 0.0f;
        #pragma unroll
        for (int b = 0; b < NBATCH; ++b) {
            float dot = 0.0f;
            #pragma unroll
            for (int e = 0; e < NEXP; ++e) {
                const float ce = ws[32 + b * NEXP + e] * ((float)NEXP / (float)(SEQ * 2));
                const float pi = ws[b * NEXP + e] / (float)SEQ;
                dot = fmaf(ce, pi, dot);
            }
            aux += dot;
        }
        out_aux[0] = aux * (1.0f / NBATCH) * ALPHA;
    }
}

// ---------------------------------------------------------------- launch
extern "C" void kernel_launch(void* const* d_in, const int* in_sizes, int n_in,
                              void* d_out, int out_size, void* d_ws, size_t ws_size,
                              hipStream_t stream) {
    const float* x = (const float*)d_in[0];   // hidden_states [4,8192,2048]
    const float* w = (const float*)d_in[1];   // weight [8,2048]

    float* out     = (float*)d_out;
    float* out_idx = out;                  // [32768,2]
    float* out_wt  = out + 2 * T_TOK;      // [32768,2]
    float* out_aux = out + 4 * T_TOK;      // [1]
    float* ws      = (float*)d_ws;

    init_ws_kernel<<<1, 64, 0, stream>>>(ws);
    gate_kernel<<<NBLK, BLOCK, 0, stream>>>(x, w, out_idx, out_wt, ws);
    finalize_kernel<<<1, 64, 0, stream>>>(ws, out_aux);
}

// Round 4
// 63.414 us; speedup vs baseline: 8.0218x; 1.2563x over previous
//
#include <hip/hip_runtime.h>

#define T_TOK   32768
#define HDIM    2048
#define NEXP    8
#define SEQ     8192
#define NBATCH  4
#define ALPHA   0.1f

#define BLOCK   512
#define TPB     64                 // tokens per block: 8 waves x 8
#define NBLK    (T_TOK / TPB)      // 512
#define H4      (HDIM / 4)         // 512 float4 per row
#define NJ      (H4 / 16)          // 32 j-phases (16-lane H split)

// ---------------------------------------------------------------- init ws
__global__ __launch_bounds__(64) void init_ws_kernel(float* ws) {
    ws[threadIdx.x] = 0.0f;        // [0..31] pi_sum, [32..63] ce_cnt
}

// ---------------------------------------------------------------- main gate
// Weights staged in LDS (64 KB) once per block; j-loop reads w via ds_read_b128
// (broadcast across the 4 token-groups = free), x streamed from HBM with
// 2-phase register lookahead. 512 thr/block, 2 blocks/CU -> 4 waves/SIMD.
__global__ __launch_bounds__(BLOCK, 4) void gate_kernel(
    const float* __restrict__ x,       // [T_TOK, HDIM]
    const float* __restrict__ w,       // [NEXP, HDIM]
    float* __restrict__ out_idx,       // [T_TOK, 2] float-encoded
    float* __restrict__ out_wt,        // [T_TOK, 2]
    float* __restrict__ ws)            // [64]
{
    __shared__ float4 wlds[NEXP * H4]; // 64 KB
    __shared__ float sacc[16];

    const int tid  = threadIdx.x;
    const int wid  = tid >> 6;
    const int lane = tid & 63;
    const int grp  = lane >> 4;
    const int col  = lane & 15;

    // stage weights: 4096 float4s, 8 per thread, coalesced
    const float4* w4 = (const float4*)w;
    #pragma unroll
    for (int i = 0; i < 8; ++i)
        wlds[tid + i * BLOCK] = w4[tid + i * BLOCK];
    if (tid < 16) sacc[tid] = 0.0f;
    __syncthreads();

    const int tok0 = blockIdx.x * TPB + wid * 8 + grp * 2;   // group's 1st token
    const int b    = (blockIdx.x * TPB) / SEQ;               // uniform per block

    const float4* xp0 = (const float4*)x + (size_t)tok0 * H4 + col;
    const float4* xp1 = xp0 + H4;                            // 2nd token

    float acc[2][NEXP];
    #pragma unroll
    for (int t = 0; t < 2; ++t)
        #pragma unroll
        for (int e = 0; e < NEXP; ++e) acc[t][e] = 0.0f;

    float4 xb0[2], xb1[2];             // x slots for even/odd j
    float4 wA[4], wB[4];               // expert halves for current j (from LDS)

    // prologue
    xb0[0] = xp0[0];        xb0[1] = xp1[0];
    xb1[0] = xp0[16];       xb1[1] = xp1[16];
    #pragma unroll
    for (int e = 0; e < 4; ++e) wA[e] = wlds[e * H4 + col];
    #pragma unroll
    for (int e = 0; e < 4; ++e) wB[e] = wlds[(e + 4) * H4 + col];

#define FMA4(ACC, XV, WV)                      \
    ACC = fmaf((XV).x, (WV).x, ACC);           \
    ACC = fmaf((XV).y, (WV).y, ACC);           \
    ACC = fmaf((XV).z, (WV).z, ACC);           \
    ACC = fmaf((XV).w, (WV).w, ACC);

#define COMPUTE_HALF(XB, WH, EBASE)            \
    _Pragma("unroll")                          \
    for (int e = 0; e < 4; ++e) {              \
        const float4 wv = WH[e];               \
        FMA4(acc[0][(EBASE) + e], XB[0], wv);  \
        FMA4(acc[1][(EBASE) + e], XB[1], wv);  \
    }

    #pragma unroll 1
    for (int jj = 0; jj < NJ - 2; jj += 2) {
        // ---- phase j = jj (even slot)
        COMPUTE_HALF(xb0, wA, 0)
        #pragma unroll
        for (int e = 0; e < 4; ++e) wA[e] = wlds[e * H4 + (jj + 1) * 16 + col];
        COMPUTE_HALF(xb0, wB, 4)
        #pragma unroll
        for (int e = 0; e < 4; ++e) wB[e] = wlds[(e + 4) * H4 + (jj + 1) * 16 + col];
        xb0[0] = xp0[(jj + 2) * 16];
        xb0[1] = xp1[(jj + 2) * 16];

        // ---- phase j = jj+1 (odd slot)
        COMPUTE_HALF(xb1, wA, 0)
        #pragma unroll
        for (int e = 0; e < 4; ++e) wA[e] = wlds[e * H4 + (jj + 2) * 16 + col];
        COMPUTE_HALF(xb1, wB, 4)
        #pragma unroll
        for (int e = 0; e < 4; ++e) wB[e] = wlds[(e + 4) * H4 + (jj + 2) * 16 + col];
        xb1[0] = xp0[(jj + 3) * 16];
        xb1[1] = xp1[(jj + 3) * 16];
    }

    // ---- peeled tail: phases NJ-2, NJ-1
    {
        COMPUTE_HALF(xb0, wA, 0)
        #pragma unroll
        for (int e = 0; e < 4; ++e) wA[e] = wlds[e * H4 + (NJ - 1) * 16 + col];
        COMPUTE_HALF(xb0, wB, 4)
        #pragma unroll
        for (int e = 0; e < 4; ++e) wB[e] = wlds[(e + 4) * H4 + (NJ - 1) * 16 + col];
        COMPUTE_HALF(xb1, wA, 0)
        COMPUTE_HALF(xb1, wB, 4)
    }

    // reduce partials across the 16-lane group (4 groups in parallel)
    #pragma unroll
    for (int t = 0; t < 2; ++t)
        #pragma unroll
        for (int e = 0; e < NEXP; ++e) {
            float v = acc[t][e];
            v += __shfl_xor(v, 1);
            v += __shfl_xor(v, 2);
            v += __shfl_xor(v, 4);
            v += __shfl_xor(v, 8);
            acc[t][e] = v;             // all 16 lanes hold both tokens' logits
        }

    // lane-local epilogue: lane col handles token (col & 1); only col<2 commits
    const int t = col & 1;
    float l[NEXP];
    #pragma unroll
    for (int e = 0; e < NEXP; ++e) l[e] = acc[t][e];

    float mx = l[0];
    #pragma unroll
    for (int e = 1; e < NEXP; ++e) mx = fmaxf(mx, l[e]);

    float p[NEXP];
    float psum = 0.0f;
    #pragma unroll
    for (int e = 0; e < NEXP; ++e) { p[e] = __expf(l[e] - mx); psum += p[e]; }
    const float inv = 1.0f / psum;
    float s[NEXP];
    #pragma unroll
    for (int e = 0; e < NEXP; ++e) s[e] = p[e] * inv;

    float s1 = s[0]; int i1 = 0;       // strict > keeps lowest index (lax.top_k)
    #pragma unroll
    for (int e = 1; e < NEXP; ++e) if (s[e] > s1) { s1 = s[e]; i1 = e; }
    float s2 = -1.0f; int i2 = 0;
    #pragma unroll
    for (int e = 0; e < NEXP; ++e) if (e != i1 && s[e] > s2) { s2 = s[e]; i2 = e; }

    const float wsum = s1 + s2 + 1e-20f;
    const float w1 = s1 / wsum;
    const float w2 = s2 / wsum;

    if (col < 2) {
        const int tok = tok0 + t;
        ((float2*)out_idx)[tok] = make_float2((float)i1, (float)i2);
        ((float2*)out_wt)[tok]  = make_float2(w1, w2);
    }

    // aux partials: lanes col 0,1 of each group carry their token's stats
    const float sel = (col < 2) ? 1.0f : 0.0f;
    #pragma unroll
    for (int e = 0; e < NEXP; ++e) {
        float pi = s[e] * sel;
        float ce = (((i1 == e) ? 1.0f : 0.0f) + ((i2 == e) ? 1.0f : 0.0f)) * sel;
        pi += __shfl_xor(pi, 1);  ce += __shfl_xor(ce, 1);   // token pair
        pi += __shfl_xor(pi, 16); ce += __shfl_xor(ce, 16);  // groups
        pi += __shfl_xor(pi, 32); ce += __shfl_xor(ce, 32);
        if (lane == 0) {
            atomicAdd(&sacc[e], pi);
            atomicAdd(&sacc[8 + e], ce);
        }
    }
    __syncthreads();
    if (tid < 8)
        atomicAdd(&ws[b * NEXP + tid], sacc[tid]);
    else if (tid < 16)
        atomicAdd(&ws[32 + b * NEXP + (tid - 8)], sacc[tid]);
}

// ---------------------------------------------------------------- finalize
__global__ __launch_bounds__(64) void finalize_kernel(const float* __restrict__ ws,
                                                      float* __restrict__ out_aux) {
    if (threadIdx.x == 0) {
        float aux = 0.0f;
        #pragma unroll
        for (int b = 0; b < NBATCH; ++b) {
            float dot = 0.0f;
            #pragma unroll
            for (int e = 0; e < NEXP; ++e) {
                const float ce = ws[32 + b * NEXP + e] * ((float)NEXP / (float)(SEQ * 2));
                const float pi = ws[b * NEXP + e] / (float)SEQ;
                dot = fmaf(ce, pi, dot);
            }
            aux += dot;
        }
        out_aux[0] = aux * (1.0f / NBATCH) * ALPHA;
    }
}

// ---------------------------------------------------------------- launch
extern "C" void kernel_launch(void* const* d_in, const int* in_sizes, int n_in,
                              void* d_out, int out_size, void* d_ws, size_t ws_size,
                              hipStream_t stream) {
    const float* x = (const float*)d_in[0];   // hidden_states [4,8192,2048]
    const float* w = (const float*)d_in[1];   // weight [8,2048]

    float* out     = (float*)d_out;
    float* out_idx = out;                  // [32768,2]
    float* out_wt  = out + 2 * T_TOK;      // [32768,2]
    float* out_aux = out + 4 * T_TOK;      // [1]
    float* ws      = (float*)d_ws;

    init_ws_kernel<<<1, 64, 0, stream>>>(ws);
    gate_kernel<<<NBLK, BLOCK, 0, stream>>>(x, w, out_idx, out_wt, ws);
    finalize_kernel<<<1, 64, 0, stream>>>(ws, out_aux);
}